// Round 12
// baseline (137.092 us; speedup 1.0000x reference)
//
#include <hip/hip_runtime.h>
#include <hip/hip_bf16.h>

// Problem geometry (fixed by reference config)
#define IN_F   4096
#define OUT_F  12288
#define OUT_PG 4096
#define M_ROWS 1024     // 2*512
#define R2     32       // GROUPS * R = 2*16
#define KS     16       // k-split factor for phase 1 (Tpart partials in d_ws)
#define NBLK   512      // grid size; 2 blocks/CU co-resident (launch_bounds enforces)

// Fused LoRA kernel: phase 1 (x @ A^T -> Tpart, + zero-fill middle block),
// device-wide spin barrier, phase 2 (T @ B^T -> out, two enabled blocks).
//
// Phase 1: 1024 A-tiles (ks 0..15 x rowgrp 0..63); block b does tiles b, b+512.
//   Tile: 4 waves x 4 rows, k-slice 256. wA chunk (32 KB) staged in LDS; inner
//   loop 32 ds_read_b128 each feeding 4 rows x 4 FMA; butterfly tree-reduce;
//   2 coalesced 256B Tpart stores/wave. Zero-fill share (16 rows x 256 cols)
//   issued first so the stores drain under compute.
// Barrier: __syncthreads drains vmcnt (stores in L2); thread0 RELEASE
//   fetch_add (agent scope -> L2 writeback) then ACQUIRE spin (agent scope ->
//   cache invalidate, makes other XCDs' Tpart writes visible). All 512 blocks
//   co-resident by construction, so the spin cannot deadlock.
// Phase 2: 1024 B-tiles (colblk 0..31 x rowblk 0..31); block b does b, b+512.
//   Tile 32 rows x 256 cols: wB staged TRANSPOSED in LDS (stride 260), T tile
//   = 16-partial sum of Tpart (2-chain ILP) in LDS; per-thread 8 rows x 4
//   cols; coalesced f4 stores.
__global__ __launch_bounds__(256, 2) void lora_fused_kernel(
    const float* __restrict__ x, const float* __restrict__ wA,
    const float* __restrict__ wB, float* __restrict__ Tpart,
    float* __restrict__ out, unsigned* __restrict__ counter) {
  __shared__ float shmem[R2 * 256];      // 32 KB; phase 2 reuses as BsT+Ts

  const int t = threadIdx.x;
  const int l = t & 63;
  const int w = t >> 6;                  // wave id

  // ---------------- Phase 1 ----------------
  float* As = shmem;
#pragma unroll 1
  for (int i2 = 0; i2 < 2; ++i2) {
    const int tau = (int)blockIdx.x + i2 * NBLK;
    const int ks = tau >> 6;             // 0..15
    const int rg = tau & 63;             // 0..63
    const int row0 = rg * 16 + w * 4;
    const int kb = ks * 256;

    // Zero-fill share of middle block: rows rg*16..+16, cols OUT_PG+ks*256..+256.
    {
      const int zrow0 = rg * 16;
      const int zcol0 = OUT_PG + ks * 256;
      const float4 z = {0.f, 0.f, 0.f, 0.f};
#pragma unroll
      for (int i = 0; i < 4; ++i) {
        const int idx = t + i * 256;
        const int zr = idx >> 6;
        const int zc = (idx & 63) * 4;
        *reinterpret_cast<float4*>(&out[(zrow0 + zr) * OUT_F + zcol0 + zc]) = z;
      }
    }

    // Prefetch x (HBM) before staging so the latency hides under it.
    float4 xv[4];
#pragma unroll
    for (int m = 0; m < 4; ++m)
      xv[m] = *reinterpret_cast<const float4*>(&x[(row0 + m) * IN_F + kb + l * 4]);

    if (i2) __syncthreads();             // protect As from previous iter's readers
    // Stage 32x256 wA chunk: 8 float4 per thread, coalesced.
#pragma unroll
    for (int i = 0; i < 8; ++i) {
      const int f = t * 4 + i * 1024;
      const int r = f >> 8, kk = f & 255;
      *reinterpret_cast<float4*>(&As[f]) =
          *reinterpret_cast<const float4*>(&wA[r * IN_F + kb + kk]);
    }
    __syncthreads();

    float acc[4][32];
#pragma unroll
    for (int m = 0; m < 4; ++m)
#pragma unroll
      for (int r = 0; r < 32; ++r) acc[m][r] = 0.f;

#pragma unroll
    for (int r = 0; r < 32; ++r) {
      const float4 av = *reinterpret_cast<const float4*>(&As[r * 256 + l * 4]);
#pragma unroll
      for (int m = 0; m < 4; ++m)
        acc[m][r] += xv[m].x * av.x + xv[m].y * av.y + xv[m].z * av.z + xv[m].w * av.w;
    }

    // Butterfly tree-reduce per row; lane ends with full sum for r = l&31.
    float v[4];
#pragma unroll
    for (int m2 = 0; m2 < 4; ++m2) {
#pragma unroll
      for (int m = 16; m >= 1; m >>= 1) {
#pragma unroll
        for (int i = 0; i < m; ++i) {
          const float a = acc[m2][i], b = acc[m2][i + m];
          const float mine   = (l & m) ? b : a;
          const float theirs = (l & m) ? a : b;
          acc[m2][i] = mine + __shfl_xor(theirs, m, 64);
        }
      }
      v[m2] = acc[m2][0] + __shfl_xor(acc[m2][0], 32, 64);
    }
#pragma unroll
    for (int p = 0; p < 2; ++p) {
      const float outv = (l < 32) ? v[2 * p] : v[2 * p + 1];
      Tpart[(ks * M_ROWS + row0 + 2 * p + (l >> 5)) * R2 + (l & 31)] = outv;
    }
  }

  // ---------------- Device-wide barrier ----------------
  __syncthreads();                       // drains vmcnt: all Tpart stores at L2
  if (t == 0) {
    __hip_atomic_fetch_add(counter, 1u, __ATOMIC_RELEASE, __HIP_MEMORY_SCOPE_AGENT);
    while (__hip_atomic_load(counter, __ATOMIC_ACQUIRE, __HIP_MEMORY_SCOPE_AGENT)
           < (unsigned)NBLK) {
      __builtin_amdgcn_s_sleep(8);
    }
  }
  __syncthreads();

  // ---------------- Phase 2 ----------------
  float* BsT = shmem;                    // [16][260], 16.6 KB
  float* Ts  = shmem + 16 * 260;         // [32][16], 2 KB
  const int cq = t & 63;
  const int rowg = t >> 6;

#pragma unroll 1
  for (int i2 = 0; i2 < 2; ++i2) {
    const int u = (int)blockIdx.x + i2 * NBLK;
    const int bxc = u >> 5;              // 0..31 col-block
    const int by  = u & 31;              // 0..31 row-block
    const int g = bxc >> 4;
    const int jbase = (bxc & 15) << 8;
    const int colbase = g ? (2 * OUT_PG + jbase) : jbase;
    const int rbase = by << 5;

    if (i2) __syncthreads();             // protect BsT/Ts from previous iter
    // Stage wB^T: 1024 f4, 4 per thread; coalesced global reads.
#pragma unroll
    for (int i = 0; i < 4; ++i) {
      const int idx = t + i * 256;
      const int c = idx >> 2, r0 = (idx & 3) * 4;
      const float4 vv = *reinterpret_cast<const float4*>(
          &wB[(g * OUT_PG + jbase + c) * 16 + r0]);
      BsT[(r0 + 0) * 260 + c] = vv.x;
      BsT[(r0 + 1) * 260 + c] = vv.y;
      BsT[(r0 + 2) * 260 + c] = vv.z;
      BsT[(r0 + 3) * 260 + c] = vv.w;
    }
    // Stage T tile with 16-partial sum (2 independent chains for ILP).
    if (t < 128) {
      const int row = t >> 2, q = t & 3;
      float4 s0 = {0.f, 0.f, 0.f, 0.f}, s1 = {0.f, 0.f, 0.f, 0.f};
#pragma unroll
      for (int ks = 0; ks < KS; ks += 2) {
        const float4 v0 = *reinterpret_cast<const float4*>(
            &Tpart[((ks + 0) * M_ROWS + rbase + row) * R2 + g * 16 + q * 4]);
        const float4 v1 = *reinterpret_cast<const float4*>(
            &Tpart[((ks + 1) * M_ROWS + rbase + row) * R2 + g * 16 + q * 4]);
        s0.x += v0.x; s0.y += v0.y; s0.z += v0.z; s0.w += v0.w;
        s1.x += v1.x; s1.y += v1.y; s1.z += v1.z; s1.w += v1.w;
      }
      Ts[row * 16 + q * 4 + 0] = s0.x + s1.x;
      Ts[row * 16 + q * 4 + 1] = s0.y + s1.y;
      Ts[row * 16 + q * 4 + 2] = s0.z + s1.z;
      Ts[row * 16 + q * 4 + 3] = s0.w + s1.w;
    }
    __syncthreads();

    float4 brow[16];
#pragma unroll
    for (int r = 0; r < 16; ++r)
      brow[r] = *reinterpret_cast<const float4*>(&BsT[r * 260 + cq * 4]);

#pragma unroll
    for (int rr = 0; rr < 8; ++rr) {
      const int rowl = rowg * 8 + rr;
      float ts[16];
#pragma unroll
      for (int q = 0; q < 4; ++q)
        *reinterpret_cast<float4*>(&ts[q * 4]) =
            *reinterpret_cast<const float4*>(&Ts[rowl * 16 + q * 4]);  // broadcast
      float a0 = 0.f, a1 = 0.f, a2 = 0.f, a3 = 0.f;
#pragma unroll
      for (int r = 0; r < 16; ++r) {
        a0 += ts[r] * brow[r].x;
        a1 += ts[r] * brow[r].y;
        a2 += ts[r] * brow[r].z;
        a3 += ts[r] * brow[r].w;
      }
      const float4 accv = {a0, a1, a2, a3};
      *reinterpret_cast<float4*>(&out[(rbase + rowl) * OUT_F + colbase + cq * 4]) = accv;
    }
  }
}

extern "C" void kernel_launch(void* const* d_in, const int* in_sizes, int n_in,
                              void* d_out, int out_size, void* d_ws, size_t ws_size,
                              hipStream_t stream) {
  const float* x  = (const float*)d_in[0];   // (2,512,4096) f32
  const float* wA = (const float*)d_in[1];   // (32,4096) f32
  const float* wB = (const float*)d_in[2];   // (8192,16) f32
  float* out = (float*)d_out;                // (2,512,12288) f32
  float* Tpart = (float*)d_ws;               // (KS,1024,32) f32 = 2 MB
  unsigned* counter = (unsigned*)(Tpart + (size_t)KS * M_ROWS * R2);

  hipMemsetAsync(counter, 0, 64, stream);    // zero the barrier counter (ws is poisoned)
  lora_fused_kernel<<<NBLK, 256, 0, stream>>>(x, wA, wB, Tpart, out, counter);
}